// Round 1
// baseline (26325.366 us; speedup 1.0000x reference)
//
#include <hip/hip_runtime.h>
#include <math.h>

// ---------------- constants ----------------
#define T_STEPS 8192
#define IN_DIM  1024
#define HD      1024
#define ZD      4096          // 4 gates * HD, order [i, j, f, o]
#define G2      64            // phase-2 workgroups (each owns 16 h-cols x 4 gates)
#define B2      512           // phase-2 block size (8 waves)

typedef short  short8 __attribute__((ext_vector_type(8)));
typedef float  f32x4  __attribute__((ext_vector_type(4)));

__device__ __forceinline__ unsigned short f2bf(float f) {
    unsigned u = __float_as_uint(f);
    unsigned r = (u + 0x7fffu + ((u >> 16) & 1u)) >> 16;
    return (unsigned short)r;
}

// ---------------- phase 0: pack Wx (rows 0..1023 of W) into bf16 tile layout ----
__global__ void wt_pack(const float* __restrict__ W, unsigned short* __restrict__ Wt) {
    int idx = blockIdx.x * 256 + threadIdx.x;      // 0 .. 4M-1
    int k = idx >> 12;                             // 0..1023
    int c = idx & 4095;                            // 0..4095
    float v = W[(size_t)k * ZD + c];               // coalesced read
    int tn = c >> 7, col = c & 127;
    int tk = k >> 5, kk = k & 31;
    Wt[(((size_t)(tn * 32 + tk) * 128 + col) << 5) + kk] = f2bf(v);
}

// ---------------- phase 1: ZX = x @ Wx + b (bf16 MFMA, fp32 accum) --------------
#define BM 128
#define BN 128
#define BKK 32
#define LDA 40    // padded LDS stride (bf16 elems)

__global__ __launch_bounds__(256) void zx_gemm(const float* __restrict__ x,
                                               const unsigned short* __restrict__ Wt,
                                               const float* __restrict__ b,
                                               float* __restrict__ zx) {
    __shared__ unsigned short As[128 * LDA];
    __shared__ unsigned short Bs[128 * LDA];
    const int tid  = threadIdx.x;
    const int wave = tid >> 6, lane = tid & 63;
    const int wr = wave & 1, wc = wave >> 1;
    const int m0 = blockIdx.y * BM, n0 = blockIdx.x * BN;
    const int quad = lane >> 4, l16 = lane & 15;

    f32x4 acc[4][4] = {};
    float bias[4];
#pragma unroll
    for (int j = 0; j < 4; ++j) bias[j] = b[n0 + wc * 64 + j * 16 + l16];

    for (int it = 0; it < IN_DIM / BKK; ++it) {
        const int k0 = it * BKK;
        // stage A: x[m0..+127][k0..+31] fp32 -> bf16 LDS
        {
            int r  = tid >> 3;          // 0..31
            int k4 = (tid & 7) * 4;
#pragma unroll
            for (int p = 0; p < 4; ++p) {
                int rr = r + p * 32;
                float4 v = *(const float4*)&x[(size_t)(m0 + rr) * IN_DIM + k0 + k4];
                unsigned p0 = (unsigned)f2bf(v.x) | ((unsigned)f2bf(v.y) << 16);
                unsigned p1 = (unsigned)f2bf(v.z) | ((unsigned)f2bf(v.w) << 16);
                *(uint2*)&As[rr * LDA + k4] = make_uint2(p0, p1);
            }
        }
        // stage B: pre-packed contiguous 8KB tile -> LDS (pad stride 40)
        {
            const uint4* src = (const uint4*)(Wt + ((size_t)(n0 >> 7) * 32 + it) * 4096);
#pragma unroll
            for (int p = 0; p < 2; ++p) {
                int id = tid * 2 + p;           // 0..511
                int col = id >> 2, kp = id & 3;
                uint4 v = src[id];
                *(uint4*)&Bs[col * LDA + kp * 8] = v;
            }
        }
        __syncthreads();
        short8 af[4], bfr[4];
#pragma unroll
        for (int i = 0; i < 4; ++i)
            af[i] = *(const short8*)&As[(wr * 64 + i * 16 + l16) * LDA + quad * 8];
#pragma unroll
        for (int j = 0; j < 4; ++j)
            bfr[j] = *(const short8*)&Bs[(wc * 64 + j * 16 + l16) * LDA + quad * 8];
#pragma unroll
        for (int i = 0; i < 4; ++i)
#pragma unroll
            for (int j = 0; j < 4; ++j)
                acc[i][j] = __builtin_amdgcn_mfma_f32_16x16x32_bf16(af[i], bfr[j], acc[i][j], 0, 0, 0);
        __syncthreads();
    }
    // epilogue: D row = quad*4 + reg, col = l16
#pragma unroll
    for (int i = 0; i < 4; ++i) {
        int row = m0 + wr * 64 + i * 16 + quad * 4;
#pragma unroll
        for (int j = 0; j < 4; ++j) {
            int col = n0 + wc * 64 + j * 16 + l16;
#pragma unroll
            for (int r = 0; r < 4; ++r)
                zx[(size_t)(row + r) * ZD + col] = acc[i][j][r] + bias[j];
        }
    }
}

// ---------------- fast activations (critical path) ----------------
__device__ __forceinline__ float sigmoid_fast(float x) {
    float e = __expf(-x);
    return __builtin_amdgcn_rcpf(1.f + e);
}
__device__ __forceinline__ float tanh_fast(float x) {
    float e = __expf(2.f * x);
    return 1.f - 2.f * __builtin_amdgcn_rcpf(e + 1.f);
}

// ---------------- phase 2: sequential recurrence (cooperative, 64 WGs) ----------
// WG g owns h-cols [16g,16g+16). Wave w owns cols 16g+2w, 16g+2w+1 (all 4 gates).
// Lane -> out = lane>>3 (col_local = out>>2, gate = out&3), sub = lane&7.
// Each lane: 128 FMAs over h[sub*128..+128) against register weights.
// In-wave butterfly reduce (shfl_xor 1,2,4) -> shfl-gather gates -> lanes 0/32
// compute activations and publish.
// h exchange: 4B packets = fp32 h with tag=(step&255) in low 8 mantissa bits
// (round-to-nearest, rel err <= 2^-17). Parity double buffer. One 8B atomic load
// per thread acquires 2 packets -> one LLC round trip, no fences, no 2nd spin.
// ONE barrier per step: lds_h parity dbuf + zx quad-buffer make stage(s) writes
// disjoint from every possibly-concurrent reader (see hazard notes inline).
#define HPAD 132   // h slice stride (floats): banks (4*sub+jj)%32 -> conflict-free b128

__global__ __launch_bounds__(B2, 2) void lstm_seq(const float* __restrict__ W,
                                                  const float* __restrict__ zx,
                                                  float* __restrict__ out,
                                                  unsigned* hslot) {
    __shared__ float lds_h[2][8 * HPAD];   // parity-double-buffered h, padded slices
    __shared__ float zx_lds[4][64];        // quad-buffered zx row for this WG

    const int g    = blockIdx.x;
    const int t    = threadIdx.x;
    const int wave = t >> 6;               // 0..7
    const int lane = t & 63;
    const int outw = lane >> 3;            // 0..7
    const int sub  = lane & 7;             // 0..7 : h slice [sub*128, +128)
    const int gate = outw & 3;             // 0..3 [i,j,f,o]
    const int cl   = outw >> 2;            // 0..1
    const int zcol = g * 16 + 2 * wave + cl + (gate << 10);

    // ---- Wh slice -> registers, PINNED (defeat rematerialization: old kernel
    // showed VGPR_Count=92 < 128 -> weights were re-loaded from L2 every step) ----
    float w[128];
#pragma unroll
    for (int j = 0; j < 128; ++j)
        w[j] = W[(size_t)(IN_DIM + (sub << 7) + j) * ZD + zcol];
#pragma unroll
    for (int j = 0; j < 128; ++j) asm volatile("" : "+v"(w[j]));

    // ---- zx prologue: wave 1 fills slots 0,1 and parks row 2 ----
    const int zoff = ((lane >> 4) << 10) + g * 16 + (lane & 15);
    float znext = 0.f;
    if (wave == 1) {
        zx_lds[0][lane] = zx[(size_t)0 * ZD + zoff];
        zx_lds[1][lane] = zx[(size_t)1 * ZD + zoff];
        znext = zx[(size_t)2 * ZD + zoff];
    }

    // thread t stages packets 2t,2t+1: slice index sub_k = t>>6 = wave, jj = 2*lane
    float* const stage_p0 = &lds_h[0][wave * HPAD + 2 * lane];
    float* const stage_p1 = &lds_h[1][wave * HPAD + 2 * lane];

    float c_state = 0.f;

    for (int s = 0; s < T_STEPS; ++s) {
        const int par = s & 1;
        // ---- zx pipeline: park row s+2 into slot (s+2)&3; issue load row s+3.
        // Hazard: slot (s+2)&3 last read at compute(s-2), which precedes every
        // wave's barrier(s-1); wave1 here has passed barrier(s-1). Safe.
        if (wave == 1) {
            if (s + 2 < T_STEPS) zx_lds[(s + 2) & 3][lane] = znext;
            if (s + 3 < T_STEPS) znext = zx[(size_t)(s + 3) * ZD + zoff];
        }
        // ---- acquire h_s: ONE 8B load = 2 tagged 4B packets ----
        {
            const unsigned long long want =
                (unsigned long long)(unsigned)(s & 255) * 0x0000000100000001ull;
            const unsigned long long* sp =
                (const unsigned long long*)(hslot + (par << 10)) + t;
            unsigned long long v;
            do {
                v = __hip_atomic_load(sp, __ATOMIC_RELAXED, __HIP_MEMORY_SCOPE_AGENT);
            } while ((v & 0x000000FF000000FFull) != want);
            unsigned lo = (unsigned)v & 0xFFFFFF00u;
            unsigned hi = (unsigned)(v >> 32) & 0xFFFFFF00u;
            float2 hv2 = make_float2(__uint_as_float(lo), __uint_as_float(hi));
            *(float2*)(par ? stage_p1 : stage_p0) = hv2;
        }
        __syncthreads();   // the ONLY barrier per step
        // ---- 128 FMAs against register weights (8-way broadcast ds_read_b128,
        // HPAD=132 -> banks 4*(sub+j4)%32: all 32 banks, conflict-free) ----
        float a0 = 0.f, a1 = 0.f, a2 = 0.f, a3 = 0.f;
        const float4* hp = (const float4*)&lds_h[par][sub * HPAD];
#pragma unroll
        for (int j4 = 0; j4 < 32; ++j4) {
            float4 hv = hp[j4];
            a0 = fmaf(w[j4 * 4 + 0], hv.x, a0);
            a1 = fmaf(w[j4 * 4 + 1], hv.y, a1);
            a2 = fmaf(w[j4 * 4 + 2], hv.z, a2);
            a3 = fmaf(w[j4 * 4 + 3], hv.w, a3);
        }
        float z = (a0 + a1) + (a2 + a3);
        // ---- in-wave butterfly over sub (bits 0..2): all 8 lanes get group sum
        z += __shfl_xor(z, 1);
        z += __shfl_xor(z, 2);
        z += __shfl_xor(z, 4);
        // ---- gather the 4 gates of this half-wave's column ----
        const int base = lane & 32;
        float zi = __shfl(z, base + 0);
        float zj = __shfl(z, base + 8);
        float zf = __shfl(z, base + 16);
        float zo = __shfl(z, base + 24);
        if ((lane & 31) == 0) {            // lanes 0 and 32: one column each
            const int cl2 = 2 * wave + (lane >> 5);
            const float* zxp = zx_lds[s & 3];
            float fg = sigmoid_fast(zf + zxp[32 + cl2] + 1.0f);   // FORGET_BIAS
            float ig = sigmoid_fast(zi + zxp[cl2]);
            float og = sigmoid_fast(zo + zxp[48 + cl2]);
            float jt = tanh_fast(zj + zxp[16 + cl2]);
            c_state = c_state * fg + ig * jt;
            float h = tanh_fast(c_state) * og;
            // pack: round h to 24-bit mantissa space, tag in low 8 bits
            unsigned hb  = (__float_as_uint(h) + 0x80u) & 0xFFFFFF00u;
            unsigned pkt = hb | (unsigned)((s + 1) & 255);
            const int hidx = g * 16 + cl2;
            __hip_atomic_store(hslot + (((s + 1) & 1) << 10) + hidx, pkt,
                               __ATOMIC_RELAXED, __HIP_MEMORY_SCOPE_AGENT);
            out[(size_t)s * HD + hidx] = h;   // off critical path
        }
        // no trailing barrier: stage(s+1) writes lds_h[par^1] (disjoint) and
        // lds_h[par] is rewritten only at stage(s+2), which is after barrier(s+1),
        // which every wave reaches only after finishing compute(s). Safe.
    }
}

// ---------------- launch ----------------
extern "C" void kernel_launch(void* const* d_in, const int* in_sizes, int n_in,
                              void* d_out, int out_size, void* d_ws, size_t ws_size,
                              hipStream_t stream) {
    const float* x = (const float*)d_in[0];   // [8192,1024]
    const float* W = (const float*)d_in[1];   // [2048,4096]
    const float* b = (const float*)d_in[2];   // [4096]
    float* out = (float*)d_out;               // [8192,1024]

    char* ws = (char*)d_ws;
    // ws layout: zx 128MB | hslot 16KB region (8KB used) | Wt 8MB
    float*          zxp   = (float*)ws;
    const size_t    ZXB   = (size_t)T_STEPS * ZD * sizeof(float);   // 134217728
    unsigned*       hslot = (unsigned*)(ws + ZXB);
    unsigned short* Wt    = (unsigned short*)(ws + ZXB + 16384);

    // h_0 = 0 with tag 0 in both parity slots (ws is poisoned each call)
    hipMemsetAsync(hslot, 0, 8192, stream);

    // phase 0: pack Wx -> bf16 tiles
    wt_pack<<<dim3((IN_DIM * ZD) / 256), dim3(256), 0, stream>>>(W, Wt);

    // phase 1: ZX = x @ Wx + b
    zx_gemm<<<dim3(ZD / BN, T_STEPS / BM), dim3(256), 0, stream>>>(x, Wt, b, zxp);

    // phase 2: sequential recurrence (cooperative for guaranteed co-residency)
    void* args[] = { (void*)&W, (void*)&zxp, (void*)&out, (void*)&hslot };
    hipLaunchCooperativeKernel((void*)lstm_seq, dim3(G2), dim3(B2), args, 0, stream);
}

// Round 2
// 15849.261 us; speedup vs baseline: 1.6610x; 1.6610x over previous
//
#include <hip/hip_runtime.h>
#include <math.h>

// ---------------- constants ----------------
#define T_STEPS 8192
#define IN_DIM  1024
#define HD      1024
#define ZD      4096          // 4 gates * HD, order [i, j, f, o]
#define G2      64            // phase-2 workgroups (each owns 16 h-cols x 4 gates)
#define B2      512           // phase-2 block size (8 waves)

typedef short  short8 __attribute__((ext_vector_type(8)));
typedef float  f32x4  __attribute__((ext_vector_type(4)));

__device__ __forceinline__ unsigned short f2bf(float f) {
    unsigned u = __float_as_uint(f);
    unsigned r = (u + 0x7fffu + ((u >> 16) & 1u)) >> 16;
    return (unsigned short)r;
}

// ---------------- phase 0: pack Wx (rows 0..1023 of W) into bf16 tile layout ----
__global__ void wt_pack(const float* __restrict__ W, unsigned short* __restrict__ Wt) {
    int idx = blockIdx.x * 256 + threadIdx.x;      // 0 .. 4M-1
    int k = idx >> 12;                             // 0..1023
    int c = idx & 4095;                            // 0..4095
    float v = W[(size_t)k * ZD + c];               // coalesced read
    int tn = c >> 7, col = c & 127;
    int tk = k >> 5, kk = k & 31;
    Wt[(((size_t)(tn * 32 + tk) * 128 + col) << 5) + kk] = f2bf(v);
}

// ---------------- phase 1: ZX = x @ Wx + b (bf16 MFMA, fp32 accum) --------------
#define BM 128
#define BN 128
#define BKK 32
#define LDA 40    // padded LDS stride (bf16 elems)

__global__ __launch_bounds__(256) void zx_gemm(const float* __restrict__ x,
                                               const unsigned short* __restrict__ Wt,
                                               const float* __restrict__ b,
                                               float* __restrict__ zx) {
    __shared__ unsigned short As[128 * LDA];
    __shared__ unsigned short Bs[128 * LDA];
    const int tid  = threadIdx.x;
    const int wave = tid >> 6, lane = tid & 63;
    const int wr = wave & 1, wc = wave >> 1;
    const int m0 = blockIdx.y * BM, n0 = blockIdx.x * BN;
    const int quad = lane >> 4, l16 = lane & 15;

    f32x4 acc[4][4] = {};
    float bias[4];
#pragma unroll
    for (int j = 0; j < 4; ++j) bias[j] = b[n0 + wc * 64 + j * 16 + l16];

    for (int it = 0; it < IN_DIM / BKK; ++it) {
        const int k0 = it * BKK;
        // stage A: x[m0..+127][k0..+31] fp32 -> bf16 LDS
        {
            int r  = tid >> 3;          // 0..31
            int k4 = (tid & 7) * 4;
#pragma unroll
            for (int p = 0; p < 4; ++p) {
                int rr = r + p * 32;
                float4 v = *(const float4*)&x[(size_t)(m0 + rr) * IN_DIM + k0 + k4];
                unsigned p0 = (unsigned)f2bf(v.x) | ((unsigned)f2bf(v.y) << 16);
                unsigned p1 = (unsigned)f2bf(v.z) | ((unsigned)f2bf(v.w) << 16);
                *(uint2*)&As[rr * LDA + k4] = make_uint2(p0, p1);
            }
        }
        // stage B: pre-packed contiguous 8KB tile -> LDS (pad stride 40)
        {
            const uint4* src = (const uint4*)(Wt + ((size_t)(n0 >> 7) * 32 + it) * 4096);
#pragma unroll
            for (int p = 0; p < 2; ++p) {
                int id = tid * 2 + p;           // 0..511
                int col = id >> 2, kp = id & 3;
                uint4 v = src[id];
                *(uint4*)&Bs[col * LDA + kp * 8] = v;
            }
        }
        __syncthreads();
        short8 af[4], bfr[4];
#pragma unroll
        for (int i = 0; i < 4; ++i)
            af[i] = *(const short8*)&As[(wr * 64 + i * 16 + l16) * LDA + quad * 8];
#pragma unroll
        for (int j = 0; j < 4; ++j)
            bfr[j] = *(const short8*)&Bs[(wc * 64 + j * 16 + l16) * LDA + quad * 8];
#pragma unroll
        for (int i = 0; i < 4; ++i)
#pragma unroll
            for (int j = 0; j < 4; ++j)
                acc[i][j] = __builtin_amdgcn_mfma_f32_16x16x32_bf16(af[i], bfr[j], acc[i][j], 0, 0, 0);
        __syncthreads();
    }
    // epilogue: D row = quad*4 + reg, col = l16
#pragma unroll
    for (int i = 0; i < 4; ++i) {
        int row = m0 + wr * 64 + i * 16 + quad * 4;
#pragma unroll
        for (int j = 0; j < 4; ++j) {
            int col = n0 + wc * 64 + j * 16 + l16;
#pragma unroll
            for (int r = 0; r < 4; ++r)
                zx[(size_t)(row + r) * ZD + col] = acc[i][j][r] + bias[j];
        }
    }
}

// ---------------- fast activations (critical path) ----------------
__device__ __forceinline__ float sigmoid_fast(float x) {
    float e = __expf(-x);
    return __builtin_amdgcn_rcpf(1.f + e);
}
__device__ __forceinline__ float tanh_fast(float x) {
    // 1 - 2/(e^{2x}+1); e=inf -> 1, e=0 -> -1 (no NaN at extremes)
    float e = __expf(2.f * x);
    return 1.f - 2.f * __builtin_amdgcn_rcpf(e + 1.f);
}

// ---------------- phase 2: sequential recurrence (cooperative, 64 WGs) ----------
// Structure = round-0 proven kernel (3-phase step, wave-0 tail, NO weight pinning:
// the compiler hoists the 128 rematerialized W loads above the spin, hiding their
// latency; pinning them spilled to scratch which thrashed L2 -> HBM. Round-1 data.)
// Changes vs round-0:
//  * h packets are 4B: fp32 h with tag=(step&255) in the low 8 mantissa bits
//    (round-to-nearest, rel err <= 2^-17). ONE 8B atomic load acquires a thread's
//    two packets -> one LLC round trip instead of two serial ones.
//  * third barrier dropped (hazard audit in comments below).
//  * wave-1 zx prefetch issued BEFORE the spin so spin latency covers it.
__global__ __launch_bounds__(B2, 2) void lstm_seq(const float* __restrict__ W,
                                                  const float* __restrict__ zx,
                                                  float* __restrict__ out,
                                                  unsigned* hslot) {
    __shared__ float lds_h[HD];
    __shared__ float pbuf[B2];
    __shared__ float zx_lds[2][64];
    const int g    = blockIdx.x;
    const int t    = threadIdx.x;
    const int seg  = t >> 6;           // 0..7
    const int lane = t & 63;
    const int gate = lane >> 4;        // 0..3  [i,j,f,o]
    const int cidx = lane & 15;
    const int zcol = g * 16 + cidx + (gate << 10);

    // Wh slice: W rows 1024..2047. NOT pinned — see header comment.
    float w[128];
#pragma unroll
    for (int j = 0; j < 128; ++j)
        w[j] = W[(size_t)(IN_DIM + (seg << 7) + j) * ZD + zcol];

    // preload zx row 0 (wave 1); consumed in phase C of step 0
    if (t >= 64 && t < 128) {
        int l = t - 64;
        zx_lds[0][l] = zx[(size_t)0 * ZD + (size_t)(l >> 4) * 1024 + g * 16 + (l & 15)];
    }

    float c_state = 0.f;

    for (int s = 0; s < T_STEPS; ++s) {
        const int par = s & 1;
        // wave 1: issue zx prefetch for step s+1 BEFORE the spin (latency cover)
        float znext = 0.f;
        if (t >= 64 && t < 128 && s + 1 < T_STEPS) {
            int l = t - 64;
            znext = zx[(size_t)(s + 1) * ZD + (size_t)(l >> 4) * 1024 + g * 16 + (l & 15)];
        }
        // ---- A: acquire h_s — ONE 8B poll = 2 tagged 4B packets {2t, 2t+1} ----
        {
            const unsigned long long want =
                (unsigned long long)(unsigned)(s & 255) * 0x0000000100000001ull;
            const unsigned long long* sp =
                (const unsigned long long*)(hslot + (par << 10)) + t;
            unsigned long long v;
            do {
                v = __hip_atomic_load(sp, __ATOMIC_RELAXED, __HIP_MEMORY_SCOPE_AGENT);
            } while ((v & 0x000000FF000000FFull) != want);
            float2 hv = make_float2(__uint_as_float((unsigned)v & 0xFFFFFF00u),
                                    __uint_as_float((unsigned)(v >> 32) & 0xFFFFFF00u));
            *(float2*)&lds_h[2 * t] = hv;   // 8B-aligned, 2-way bank alias (free)
        }
        __syncthreads();                         // sync1: lds_h ready
        // ---- B: 128 FMAs against register/hoisted weights ----
        float a0 = 0.f, a1 = 0.f, a2 = 0.f, a3 = 0.f;
        const float4* hp = (const float4*)&lds_h[seg << 7];
#pragma unroll
        for (int j4 = 0; j4 < 32; ++j4) {
            float4 hv = hp[j4];
            a0 = fmaf(w[j4 * 4 + 0], hv.x, a0);
            a1 = fmaf(w[j4 * 4 + 1], hv.y, a1);
            a2 = fmaf(w[j4 * 4 + 2], hv.z, a2);
            a3 = fmaf(w[j4 * 4 + 3], hv.w, a3);
        }
        pbuf[t] = (a0 + a1) + (a2 + a3);
        if (t >= 64 && t < 128)                  // park prefetched zx for next step
            zx_lds[(s + 1) & 1][t - 64] = znext;
        __syncthreads();                         // sync2: pbuf ready
        // ---- C: wave 0 reduces, gates, publishes ----
        if (t < 64) {
            float z = zx_lds[s & 1][t];
#pragma unroll
            for (int ss = 0; ss < 8; ++ss) z += pbuf[(ss << 6) + t];
            float zi = __shfl(z, cidx);
            float zj = __shfl(z, 16 + cidx);
            float zf = __shfl(z, 32 + cidx);
            float zo = __shfl(z, 48 + cidx);
            if (t < 16) {
                float fg = sigmoid_fast(zf + 1.0f);   // FORGET_BIAS = 1.0
                float ig = sigmoid_fast(zi);
                float og = sigmoid_fast(zo);
                c_state = c_state * fg + ig * tanh_fast(zj);
                float h = tanh_fast(c_state) * og;
                // pack: round h to 24-bit mantissa, tag in low 8 bits; 16 lanes
                // publish one contiguous 64B line per WG
                unsigned hb  = (__float_as_uint(h) + 0x80u) & 0xFFFFFF00u;
                unsigned pkt = hb | (unsigned)((s + 1) & 255);
                __hip_atomic_store(hslot + (((s + 1) & 1) << 10) + g * 16 + t, pkt,
                                   __ATOMIC_RELAXED, __HIP_MEMORY_SCOPE_AGENT);
                out[(size_t)s * HD + g * 16 + t] = h;  // off critical path
            }
        }
        // NO third barrier. Hazard audit:
        //  * lds_h: written at A(s+1), which every thread reaches only after
        //    sync2(s); all B(s) reads precede sync2(s). Safe.
        //  * pbuf: written at B(s+1) after sync1(s+1); sync1(s+1) release requires
        //    wave0's arrival, which is after its C(s) pbuf reads. Safe.
        //  * zx_lds[s&1]: read at C(s) by wave0; next written at B(s+1) (slot
        //    (s+2)&1 == s&1) — also after sync1(s+1). Safe.
    }
}

// ---------------- launch ----------------
extern "C" void kernel_launch(void* const* d_in, const int* in_sizes, int n_in,
                              void* d_out, int out_size, void* d_ws, size_t ws_size,
                              hipStream_t stream) {
    const float* x = (const float*)d_in[0];   // [8192,1024]
    const float* W = (const float*)d_in[1];   // [2048,4096]
    const float* b = (const float*)d_in[2];   // [4096]
    float* out = (float*)d_out;               // [8192,1024]

    char* ws = (char*)d_ws;
    // ws layout: zx 128MB | hslot 16KB region (8KB used) | Wt 8MB
    float*          zxp   = (float*)ws;
    const size_t    ZXB   = (size_t)T_STEPS * ZD * sizeof(float);   // 134217728
    unsigned*       hslot = (unsigned*)(ws + ZXB);
    unsigned short* Wt    = (unsigned short*)(ws + ZXB + 16384);

    // h_0 = 0 with tag 0 in both parity slots (ws is poisoned each call)
    hipMemsetAsync(hslot, 0, 8192, stream);

    // phase 0: pack Wx -> bf16 tiles
    wt_pack<<<dim3((IN_DIM * ZD) / 256), dim3(256), 0, stream>>>(W, Wt);

    // phase 1: ZX = x @ Wx + b
    zx_gemm<<<dim3(ZD / BN, T_STEPS / BM), dim3(256), 0, stream>>>(x, Wt, b, zxp);

    // phase 2: sequential recurrence (cooperative for guaranteed co-residency)
    void* args[] = { (void*)&W, (void*)&zxp, (void*)&out, (void*)&hslot };
    hipLaunchCooperativeKernel((void*)lstm_seq, dim3(G2), dim3(B2), args, 0, stream);
}

// Round 3
// 15494.414 us; speedup vs baseline: 1.6990x; 1.0229x over previous
//
#include <hip/hip_runtime.h>
#include <hip/hip_fp16.h>
#include <math.h>

// ---------------- constants ----------------
#define T_STEPS 8192
#define IN_DIM  1024
#define HD      1024
#define ZD      4096          // 4 gates * HD, order [i, j, f, o]
#define G2      64            // phase-2 workgroups (each owns 16 h-cols x 4 gates)
#define B2      512           // phase-2 block size (8 waves)

typedef short  short8 __attribute__((ext_vector_type(8)));
typedef float  f32x4  __attribute__((ext_vector_type(4)));

__device__ __forceinline__ unsigned short f2bf(float f) {
    unsigned u = __float_as_uint(f);
    unsigned r = (u + 0x7fffu + ((u >> 16) & 1u)) >> 16;
    return (unsigned short)r;
}

// ---------------- phase 0: pack Wx (rows 0..1023 of W) into bf16 tile layout ----
__global__ void wt_pack(const float* __restrict__ W, unsigned short* __restrict__ Wt) {
    int idx = blockIdx.x * 256 + threadIdx.x;      // 0 .. 4M-1
    int k = idx >> 12;                             // 0..1023
    int c = idx & 4095;                            // 0..4095
    float v = W[(size_t)k * ZD + c];               // coalesced read
    int tn = c >> 7, col = c & 127;
    int tk = k >> 5, kk = k & 31;
    Wt[(((size_t)(tn * 32 + tk) * 128 + col) << 5) + kk] = f2bf(v);
}

// ---------------- phase 0b: pack Wh (rows 1024..2047) into fp16 per-thread runs --
// Whp[(zcol*8+seg)*64 + j] = half2( Wh[seg*128+2j][zcol], Wh[seg*128+2j+1][zcol] )
// Runs AFTER zx_gemm, overwriting the then-dead Wt region (no extra workspace).
__global__ void whp_pack(const float* __restrict__ W, unsigned* __restrict__ Whp) {
    int i = blockIdx.x * 256 + threadIdx.x;   // 0..32767
    int zcol = i & 4095;
    int seg  = i >> 12;                       // 0..7
    const float* src = W + (size_t)(IN_DIM + (seg << 7)) * ZD + zcol; // lane-coalesced
    unsigned* dst = Whp + ((size_t)zcol * 8 + seg) * 64;              // 256B/thread
    for (int j = 0; j < 64; ++j) {
        float v0 = src[(size_t)(2 * j) * ZD];
        float v1 = src[(size_t)(2 * j + 1) * ZD];
        unsigned lo = (unsigned)__half_as_ushort(__float2half(v0));
        unsigned hi = (unsigned)__half_as_ushort(__float2half(v1));
        dst[j] = lo | (hi << 16);
    }
}

// ---------------- phase 1: ZX = x @ Wx + b (bf16 MFMA, fp32 accum) --------------
#define BM 128
#define BN 128
#define BKK 32
#define LDA 40    // padded LDS stride (bf16 elems)

__global__ __launch_bounds__(256) void zx_gemm(const float* __restrict__ x,
                                               const unsigned short* __restrict__ Wt,
                                               const float* __restrict__ b,
                                               float* __restrict__ zx) {
    __shared__ unsigned short As[128 * LDA];
    __shared__ unsigned short Bs[128 * LDA];
    const int tid  = threadIdx.x;
    const int wave = tid >> 6, lane = tid & 63;
    const int wr = wave & 1, wc = wave >> 1;
    const int m0 = blockIdx.y * BM, n0 = blockIdx.x * BN;
    const int quad = lane >> 4, l16 = lane & 15;

    f32x4 acc[4][4] = {};
    float bias[4];
#pragma unroll
    for (int j = 0; j < 4; ++j) bias[j] = b[n0 + wc * 64 + j * 16 + l16];

    for (int it = 0; it < IN_DIM / BKK; ++it) {
        const int k0 = it * BKK;
        // stage A: x[m0..+127][k0..+31] fp32 -> bf16 LDS
        {
            int r  = tid >> 3;          // 0..31
            int k4 = (tid & 7) * 4;
#pragma unroll
            for (int p = 0; p < 4; ++p) {
                int rr = r + p * 32;
                float4 v = *(const float4*)&x[(size_t)(m0 + rr) * IN_DIM + k0 + k4];
                unsigned p0 = (unsigned)f2bf(v.x) | ((unsigned)f2bf(v.y) << 16);
                unsigned p1 = (unsigned)f2bf(v.z) | ((unsigned)f2bf(v.w) << 16);
                *(uint2*)&As[rr * LDA + k4] = make_uint2(p0, p1);
            }
        }
        // stage B: pre-packed contiguous 8KB tile -> LDS (pad stride 40)
        {
            const uint4* src = (const uint4*)(Wt + ((size_t)(n0 >> 7) * 32 + it) * 4096);
#pragma unroll
            for (int p = 0; p < 2; ++p) {
                int id = tid * 2 + p;           // 0..511
                int col = id >> 2, kp = id & 3;
                uint4 v = src[id];
                *(uint4*)&Bs[col * LDA + kp * 8] = v;
            }
        }
        __syncthreads();
        short8 af[4], bfr[4];
#pragma unroll
        for (int i = 0; i < 4; ++i)
            af[i] = *(const short8*)&As[(wr * 64 + i * 16 + l16) * LDA + quad * 8];
#pragma unroll
        for (int j = 0; j < 4; ++j)
            bfr[j] = *(const short8*)&Bs[(wc * 64 + j * 16 + l16) * LDA + quad * 8];
#pragma unroll
        for (int i = 0; i < 4; ++i)
#pragma unroll
            for (int j = 0; j < 4; ++j)
                acc[i][j] = __builtin_amdgcn_mfma_f32_16x16x32_bf16(af[i], bfr[j], acc[i][j], 0, 0, 0);
        __syncthreads();
    }
    // epilogue: D row = quad*4 + reg, col = l16
#pragma unroll
    for (int i = 0; i < 4; ++i) {
        int row = m0 + wr * 64 + i * 16 + quad * 4;
#pragma unroll
        for (int j = 0; j < 4; ++j) {
            int col = n0 + wc * 64 + j * 16 + l16;
#pragma unroll
            for (int r = 0; r < 4; ++r)
                zx[(size_t)(row + r) * ZD + col] = acc[i][j][r] + bias[j];
        }
    }
}

// ---------------- fast activations (critical path) ----------------
__device__ __forceinline__ float sigmoid_fast(float x) {
    float e = __expf(-x);
    return __builtin_amdgcn_rcpf(1.f + e);
}
__device__ __forceinline__ float tanh_fast(float x) {
    // 1 - 2/(e^{2x}+1); e=inf -> 1, e=0 -> -1 (no NaN at extremes)
    float e = __expf(2.f * x);
    return 1.f - 2.f * __builtin_amdgcn_rcpf(e + 1.f);
}

// ---------------- phase 2: sequential recurrence (cooperative, 64 WGs) ----------
// Changes vs round-2 (each independently audited):
//  * Wh REGISTER-RESIDENT as fp16 pairs: 64 pinned dwords/thread (~110 VGPR total,
//    fits the 128-VGPR cap that round-1's 128-fp32 pin blew through). Kills the
//    256KB/WG/step L2 weight restream that VGPR_Count=96 exposed (~1 us/step).
//    fp16 weight error (2^-11 rel, |w|<~0.15) << existing bf16-GEMM error.
//  * sync1 REMOVED: wave w polls exactly h[128w..128w+128) and its FMA reads
//    exactly that slice -> producer wave == consumer wave, LDS ordering is
//    intra-wave lgkmcnt only. ONE barrier per step (pbuf parity-double-buffered).
//    Early-published h slices start their FMA before the slowest producer lands.
// Hazard audit (single sync2 per step):
//  * lds_h[slice w]: written at A(s) and read at B(s) ONLY by wave w. In-order
//    within the wave. No cross-wave access, no barrier needed, single-buffered.
//  * pbuf[par]: written at B(s) (pre-sync2(s)), read by wave0 at C(s)
//    (post-sync2(s)). Next write to the same slot is B(s+2), which follows
//    sync2(s+1); wave0 arrives at sync2(s+1) only after C(s). Safe.
//  * zx_lds[par]: read by wave0 at C(s) slot s&1; wave1 writes slot (s+1)&1 at
//    B(s+1) (disjoint); slot s&1 rewritten at B(s+2) > sync2(s+1) > C(s). Safe.
__global__ __launch_bounds__(B2, 2) void lstm_seq(const unsigned* __restrict__ whp,
                                                  const float* __restrict__ zx,
                                                  float* __restrict__ out,
                                                  unsigned* hslot) {
    __shared__ float lds_h[HD];
    __shared__ float pbuf[2][B2];
    __shared__ float zx_lds[2][64];
    const int g    = blockIdx.x;
    const int t    = threadIdx.x;
    const int seg  = t >> 6;           // 0..7 == wave index
    const int lane = t & 63;
    const int gate = lane >> 4;        // 0..3  [i,j,f,o]
    const int cidx = lane & 15;
    const int zcol = g * 16 + cidx + (gate << 10);

    // ---- Wh slice -> 64 packed-fp16 dwords, pinned in VGPRs ----
    unsigned wp[64];
    {
        const unsigned* wsrc = whp + ((size_t)zcol * 8 + seg) * 64;
#pragma unroll
        for (int j = 0; j < 64; ++j) wp[j] = wsrc[j];
    }
#pragma unroll
    for (int j = 0; j < 64; ++j) asm volatile("" : "+v"(wp[j]));

    // preload zx row 0 (wave 1); consumed in phase C of step 0
    if (t >= 64 && t < 128) {
        int l = t - 64;
        zx_lds[0][l] = zx[(size_t)0 * ZD + (size_t)(l >> 4) * 1024 + g * 16 + (l & 15)];
    }
    __syncthreads();   // cover zx_lds[0] for step-0 C-phase (outside the loop)

    float c_state = 0.f;

    for (int s = 0; s < T_STEPS; ++s) {
        const int par = s & 1;
        // wave 1: issue zx prefetch for step s+1 BEFORE the spin (latency cover)
        float znext = 0.f;
        if (t >= 64 && t < 128 && s + 1 < T_STEPS) {
            int l = t - 64;
            znext = zx[(size_t)(s + 1) * ZD + (size_t)(l >> 4) * 1024 + g * 16 + (l & 15)];
        }
        // ---- A: acquire h slice — ONE 8B poll = 2 tagged 4B packets {2t,2t+1} ----
        {
            const unsigned long long want =
                (unsigned long long)(unsigned)(s & 255) * 0x0000000100000001ull;
            const unsigned long long* sp =
                (const unsigned long long*)(hslot + (par << 10)) + t;
            unsigned long long v;
            do {
                v = __hip_atomic_load(sp, __ATOMIC_RELAXED, __HIP_MEMORY_SCOPE_AGENT);
            } while ((v & 0x000000FF000000FFull) != want);
            float2 hv = make_float2(__uint_as_float((unsigned)v & 0xFFFFFF00u),
                                    __uint_as_float((unsigned)(v >> 32) & 0xFFFFFF00u));
            *(float2*)&lds_h[2 * t] = hv;   // own-wave slice; intra-wave ordering only
        }
        // ---- B: 128 FMAs against register-resident fp16 weights ----
        float a0 = 0.f, a1 = 0.f, a2 = 0.f, a3 = 0.f;
        const float4* hp = (const float4*)&lds_h[seg << 7];
#pragma unroll
        for (int j4 = 0; j4 < 32; ++j4) {
            float4 hv = hp[j4];
            unsigned p0 = wp[2 * j4], p1 = wp[2 * j4 + 1];
            float w0 = __half2float(__ushort_as_half((unsigned short)p0));
            float w1 = __half2float(__ushort_as_half((unsigned short)(p0 >> 16)));
            float w2 = __half2float(__ushort_as_half((unsigned short)p1));
            float w3 = __half2float(__ushort_as_half((unsigned short)(p1 >> 16)));
            a0 = fmaf(w0, hv.x, a0);
            a1 = fmaf(w1, hv.y, a1);
            a2 = fmaf(w2, hv.z, a2);
            a3 = fmaf(w3, hv.w, a3);
        }
        pbuf[par][t] = (a0 + a1) + (a2 + a3);
        if (t >= 64 && t < 128)                  // park prefetched zx for next step
            zx_lds[(s + 1) & 1][t - 64] = znext;
        __syncthreads();                         // the ONLY barrier per step
        // ---- C: wave 0 reduces, gates, publishes ----
        if (t < 64) {
            float z = zx_lds[s & 1][t];
#pragma unroll
            for (int ss = 0; ss < 8; ++ss) z += pbuf[par][(ss << 6) + t];
            float zi = __shfl(z, cidx);
            float zj = __shfl(z, 16 + cidx);
            float zf = __shfl(z, 32 + cidx);
            float zo = __shfl(z, 48 + cidx);
            if (t < 16) {
                float fg = sigmoid_fast(zf + 1.0f);   // FORGET_BIAS = 1.0
                float ig = sigmoid_fast(zi);
                float og = sigmoid_fast(zo);
                c_state = c_state * fg + ig * tanh_fast(zj);
                float h = tanh_fast(c_state) * og;
                // pack: round h to 24-bit mantissa, tag in low 8 bits; 16 lanes
                // publish one contiguous 64B line per WG
                unsigned hb  = (__float_as_uint(h) + 0x80u) & 0xFFFFFF00u;
                unsigned pkt = hb | (unsigned)((s + 1) & 255);
                __hip_atomic_store(hslot + (((s + 1) & 1) << 10) + g * 16 + t, pkt,
                                   __ATOMIC_RELAXED, __HIP_MEMORY_SCOPE_AGENT);
                out[(size_t)s * HD + g * 16 + t] = h;  // off critical path
            }
        }
    }
}

// ---------------- launch ----------------
extern "C" void kernel_launch(void* const* d_in, const int* in_sizes, int n_in,
                              void* d_out, int out_size, void* d_ws, size_t ws_size,
                              hipStream_t stream) {
    const float* x = (const float*)d_in[0];   // [8192,1024]
    const float* W = (const float*)d_in[1];   // [2048,4096]
    const float* b = (const float*)d_in[2];   // [4096]
    float* out = (float*)d_out;               // [8192,1024]

    char* ws = (char*)d_ws;
    // ws layout: zx 128MB | hslot 16KB region (8KB used) | Wt/Whp 8MB (time-shared)
    float*          zxp   = (float*)ws;
    const size_t    ZXB   = (size_t)T_STEPS * ZD * sizeof(float);   // 134217728
    unsigned*       hslot = (unsigned*)(ws + ZXB);
    unsigned short* Wt    = (unsigned short*)(ws + ZXB + 16384);
    unsigned*       Whp   = (unsigned*)(ws + ZXB + 16384);          // reuses Wt region

    // h_0 = 0 with tag 0 in both parity slots (ws is poisoned each call)
    hipMemsetAsync(hslot, 0, 8192, stream);

    // phase 0: pack Wx -> bf16 tiles
    wt_pack<<<dim3((IN_DIM * ZD) / 256), dim3(256), 0, stream>>>(W, Wt);

    // phase 1: ZX = x @ Wx + b
    zx_gemm<<<dim3(ZD / BN, T_STEPS / BM), dim3(256), 0, stream>>>(x, Wt, b, zxp);

    // phase 0b: pack Wh -> fp16 pairs into the now-dead Wt region (stream-ordered)
    whp_pack<<<dim3(128), dim3(256), 0, stream>>>(W, Whp);

    // phase 2: sequential recurrence (cooperative for guaranteed co-residency)
    void* args[] = { (void*)&Whp, (void*)&zxp, (void*)&out, (void*)&hslot };
    hipLaunchCooperativeKernel((void*)lstm_seq, dim3(G2), dim3(B2), args, 0, stream);
}

// Round 5
// 12238.091 us; speedup vs baseline: 2.1511x; 1.2661x over previous
//
#include <hip/hip_runtime.h>
#include <hip/hip_fp16.h>
#include <math.h>

// ---------------- constants ----------------
#define T_STEPS 8192
#define IN_DIM  1024
#define HD      1024
#define ZD      4096          // 4 gates * HD, order [i, j, f, o]
#define G2      64            // phase-2 workgroups (each owns 16 h-cols x 4 gates)
#define B2      512           // phase-2 block size (8 waves)

typedef short  short8 __attribute__((ext_vector_type(8)));
typedef float  f32x4  __attribute__((ext_vector_type(4)));
typedef unsigned uint4v __attribute__((ext_vector_type(4)));
typedef _Float16 h2v __attribute__((ext_vector_type(2)));

__device__ __forceinline__ unsigned short f2bf(float f) {
    unsigned u = __float_as_uint(f);
    unsigned r = (u + 0x7fffu + ((u >> 16) & 1u)) >> 16;
    return (unsigned short)r;
}

// pack 2 fp32 -> 2 fp16 (RTZ) as a dword; bit_cast bridges __fp16 vs _Float16 types
__device__ __forceinline__ unsigned pk16(float a, float b) {
    return __builtin_bit_cast(unsigned, __builtin_amdgcn_cvt_pkrtz(a, b));
}

// ---------------- phase 0: pack Wx (rows 0..1023 of W) into bf16 tile layout ----
__global__ void wt_pack(const float* __restrict__ W, unsigned short* __restrict__ Wt) {
    int idx = blockIdx.x * 256 + threadIdx.x;      // 0 .. 4M-1
    int k = idx >> 12;                             // 0..1023
    int c = idx & 4095;                            // 0..4095
    float v = W[(size_t)k * ZD + c];               // coalesced read
    int tn = c >> 7, col = c & 127;
    int tk = k >> 5, kk = k & 31;
    Wt[(((size_t)(tn * 32 + tk) * 128 + col) << 5) + kk] = f2bf(v);
}

// ---------------- phase 0b: pack Wh (rows 1024..2047) into fp16 per-thread runs --
// Whp[(zcol*8+seg)*64 + j] = half2( Wh[seg*128+2j][zcol], Wh[seg*128+2j+1][zcol] )
// Runs AFTER zx_gemm, overwriting the then-dead Wt region (no extra workspace).
__global__ void whp_pack(const float* __restrict__ W, unsigned* __restrict__ Whp) {
    int i = blockIdx.x * 256 + threadIdx.x;   // 0..32767
    int zcol = i & 4095;
    int seg  = i >> 12;                       // 0..7
    const float* src = W + (size_t)(IN_DIM + (seg << 7)) * ZD + zcol; // lane-coalesced
    unsigned* dst = Whp + ((size_t)zcol * 8 + seg) * 64;              // 256B/thread
    for (int j = 0; j < 64; ++j) {
        float v0 = src[(size_t)(2 * j) * ZD];
        float v1 = src[(size_t)(2 * j + 1) * ZD];
        unsigned lo = (unsigned)__half_as_ushort(__float2half(v0));
        unsigned hi = (unsigned)__half_as_ushort(__float2half(v1));
        dst[j] = lo | (hi << 16);
    }
}

// ---------------- phase 1: ZX = x @ Wx + b (bf16 MFMA, fp32 accum) --------------
#define BM 128
#define BN 128
#define BKK 32
#define LDA 40    // padded LDS stride (bf16 elems)

__global__ __launch_bounds__(256) void zx_gemm(const float* __restrict__ x,
                                               const unsigned short* __restrict__ Wt,
                                               const float* __restrict__ b,
                                               float* __restrict__ zx) {
    __shared__ unsigned short As[128 * LDA];
    __shared__ unsigned short Bs[128 * LDA];
    const int tid  = threadIdx.x;
    const int wave = tid >> 6, lane = tid & 63;
    const int wr = wave & 1, wc = wave >> 1;
    const int m0 = blockIdx.y * BM, n0 = blockIdx.x * BN;
    const int quad = lane >> 4, l16 = lane & 15;

    f32x4 acc[4][4] = {};
    float bias[4];
#pragma unroll
    for (int j = 0; j < 4; ++j) bias[j] = b[n0 + wc * 64 + j * 16 + l16];

    for (int it = 0; it < IN_DIM / BKK; ++it) {
        const int k0 = it * BKK;
        // stage A: x[m0..+127][k0..+31] fp32 -> bf16 LDS
        {
            int r  = tid >> 3;          // 0..31
            int k4 = (tid & 7) * 4;
#pragma unroll
            for (int p = 0; p < 4; ++p) {
                int rr = r + p * 32;
                float4 v = *(const float4*)&x[(size_t)(m0 + rr) * IN_DIM + k0 + k4];
                unsigned p0 = (unsigned)f2bf(v.x) | ((unsigned)f2bf(v.y) << 16);
                unsigned p1 = (unsigned)f2bf(v.z) | ((unsigned)f2bf(v.w) << 16);
                *(uint2*)&As[rr * LDA + k4] = make_uint2(p0, p1);
            }
        }
        // stage B: pre-packed contiguous 8KB tile -> LDS (pad stride 40)
        {
            const uint4* src = (const uint4*)(Wt + ((size_t)(n0 >> 7) * 32 + it) * 4096);
#pragma unroll
            for (int p = 0; p < 2; ++p) {
                int id = tid * 2 + p;           // 0..511
                int col = id >> 2, kp = id & 3;
                uint4 v = src[id];
                *(uint4*)&Bs[col * LDA + kp * 8] = v;
            }
        }
        __syncthreads();
        short8 af[4], bfr[4];
#pragma unroll
        for (int i = 0; i < 4; ++i)
            af[i] = *(const short8*)&As[(wr * 64 + i * 16 + l16) * LDA + quad * 8];
#pragma unroll
        for (int j = 0; j < 4; ++j)
            bfr[j] = *(const short8*)&Bs[(wc * 64 + j * 16 + l16) * LDA + quad * 8];
#pragma unroll
        for (int i = 0; i < 4; ++i)
#pragma unroll
            for (int j = 0; j < 4; ++j)
                acc[i][j] = __builtin_amdgcn_mfma_f32_16x16x32_bf16(af[i], bfr[j], acc[i][j], 0, 0, 0);
        __syncthreads();
    }
    // epilogue: D row = quad*4 + reg, col = l16
#pragma unroll
    for (int i = 0; i < 4; ++i) {
        int row = m0 + wr * 64 + i * 16 + quad * 4;
#pragma unroll
        for (int j = 0; j < 4; ++j) {
            int col = n0 + wc * 64 + j * 16 + l16;
#pragma unroll
            for (int r = 0; r < 4; ++r)
                zx[(size_t)(row + r) * ZD + col] = acc[i][j][r] + bias[j];
        }
    }
}

// ---------------- fast activations (critical path) ----------------
__device__ __forceinline__ float sigmoid_fast(float x) {
    float e = __expf(-x);
    return __builtin_amdgcn_rcpf(1.f + e);
}
__device__ __forceinline__ float tanh_fast(float x) {
    // 1 - 2/(e^{2x}+1); e=inf -> 1, e=0 -> -1 (no NaN at extremes)
    float e = __expf(2.f * x);
    return 1.f - 2.f * __builtin_amdgcn_rcpf(e + 1.f);
}

// ---------------- phase 2: sequential recurrence (cooperative, 64 WGs) ----------
// Round-4 theory: step = ~0.3us VALU + ~1.4us spin-detect TAIL latency (LLC
// congestion from 32768 redundant 8B polls). Changes:
//  * h staged in LDS as packed fp16 pairs; B-phase = 64 v_dot2_f32_f16 instead of
//    128 fma + 128 cvt (VALU/step ~600 -> ~250 cy). fp16-h error ~3e-4*|h| through
//    |w|~0.02 over 1024 terms => z perturbation ~5e-5 << tolerance. The tag byte
//    sits entirely below fp16 precision -> convert raw packet floats, no masking.
//  * polls are 16B global_load_dwordx4 sc0 sc1 (LLC-coherent, same path the
//    atomic lowers to): lanes 0..31 of each wave poll the wave's OWN 128-col
//    slice (4 tagged packets per poll). Requests/round halve (32768->16384),
//    per-line pollers halve. Per-packet tags make torn publishes a retry, not a
//    hazard. Own-wave staging preserved -> still no sync1, ONE barrier per step.
// Hazard audit unchanged from round 3 (pbuf parity-dbuf, zx_lds parity, lds_hh
// own-wave in-order).
__global__ __launch_bounds__(B2, 2) void lstm_seq(const unsigned* __restrict__ whp,
                                                  const float* __restrict__ zx,
                                                  float* __restrict__ out,
                                                  unsigned* hslot) {
    __shared__ unsigned lds_hh[512];       // fp16-packed h: dword d = {h[2d], h[2d+1]}
    __shared__ float pbuf[2][B2];
    __shared__ float zx_lds[2][64];
    const int g    = blockIdx.x;
    const int t    = threadIdx.x;
    const int seg  = t >> 6;           // 0..7 == wave index
    const int lane = t & 63;
    const int gate = lane >> 4;        // 0..3  [i,j,f,o]
    const int cidx = lane & 15;
    const int zcol = g * 16 + cidx + (gate << 10);

    // ---- Wh slice -> 64 packed-fp16 dwords, pinned in VGPRs ----
    unsigned wp[64];
    {
        const unsigned* wsrc = whp + ((size_t)zcol * 8 + seg) * 64;
#pragma unroll
        for (int j = 0; j < 64; ++j) wp[j] = wsrc[j];
    }
#pragma unroll
    for (int j = 0; j < 64; ++j) asm volatile("" : "+v"(wp[j]));

    // preload zx row 0 (wave 1); consumed in phase C of step 0
    if (t >= 64 && t < 128) {
        int l = t - 64;
        zx_lds[0][l] = zx[(size_t)0 * ZD + (size_t)(l >> 4) * 1024 + g * 16 + (l & 15)];
    }
    __syncthreads();   // cover zx_lds[0] for step-0 C-phase (outside the loop)

    float c_state = 0.f;

    for (int s = 0; s < T_STEPS; ++s) {
        const int par = s & 1;
        // wave 1: issue zx prefetch for step s+1 BEFORE the spin (latency cover;
        // the spin's vmcnt(0) completes it during the first poll iteration)
        float znext = 0.f;
        if (t >= 64 && t < 128 && s + 1 < T_STEPS) {
            int l = t - 64;
            znext = zx[(size_t)(s + 1) * ZD + (size_t)(l >> 4) * 1024 + g * 16 + (l & 15)];
        }
        // ---- A: acquire own slice — lanes 0..31 poll 16B = 4 tagged packets ----
        if (lane < 32) {
            const unsigned want = (unsigned)(s & 255);
            const unsigned* ap = hslot + (par << 10) + (seg << 7) + (lane << 2);
            uint4v pv;
            for (;;) {
                asm volatile("global_load_dwordx4 %0, %1, off sc0 sc1\n\t"
                             "s_waitcnt vmcnt(0)"
                             : "=v"(pv) : "v"(ap) : "memory");
                unsigned bad = ((pv.x ^ want) | (pv.y ^ want) |
                                (pv.z ^ want) | (pv.w ^ want)) & 255u;
                if (bad == 0) break;
            }
            // convert 4 fp32 packets -> 2 packed-fp16 dwords (tag bits sub-ulp)
            unsigned d0 = pk16(__uint_as_float(pv.x), __uint_as_float(pv.y));
            unsigned d1 = pk16(__uint_as_float(pv.z), __uint_as_float(pv.w));
            *(uint2*)&lds_hh[(seg << 6) + 2 * lane] = make_uint2(d0, d1);
        }
        // ---- B: 64 dot2 against register-resident fp16 weights (own slice) ----
        float a0 = 0.f, a1 = 0.f, a2 = 0.f, a3 = 0.f;
        const uint4* hp = (const uint4*)&lds_hh[seg << 6];
#pragma unroll
        for (int j = 0; j < 16; ++j) {
            uint4 hv = hp[j];    // same addr across wave: LDS broadcast, no conflict
            a0 = __builtin_amdgcn_fdot2(__builtin_bit_cast(h2v, wp[4 * j + 0]),
                                        __builtin_bit_cast(h2v, hv.x), a0, false);
            a1 = __builtin_amdgcn_fdot2(__builtin_bit_cast(h2v, wp[4 * j + 1]),
                                        __builtin_bit_cast(h2v, hv.y), a1, false);
            a2 = __builtin_amdgcn_fdot2(__builtin_bit_cast(h2v, wp[4 * j + 2]),
                                        __builtin_bit_cast(h2v, hv.z), a2, false);
            a3 = __builtin_amdgcn_fdot2(__builtin_bit_cast(h2v, wp[4 * j + 3]),
                                        __builtin_bit_cast(h2v, hv.w), a3, false);
        }
        pbuf[par][t] = (a0 + a1) + (a2 + a3);
        if (t >= 64 && t < 128)                  // park prefetched zx for next step
            zx_lds[(s + 1) & 1][t - 64] = znext;
        __syncthreads();                         // the ONLY barrier per step
        // ---- C: wave 0 reduces, gates, publishes ----
        if (t < 64) {
            float z = zx_lds[s & 1][t];
#pragma unroll
            for (int ss = 0; ss < 8; ++ss) z += pbuf[par][(ss << 6) + t];
            float zi = __shfl(z, cidx);
            float zj = __shfl(z, 16 + cidx);
            float zf = __shfl(z, 32 + cidx);
            float zo = __shfl(z, 48 + cidx);
            if (t < 16) {
                float fg = sigmoid_fast(zf + 1.0f);   // FORGET_BIAS = 1.0
                float ig = sigmoid_fast(zi);
                float og = sigmoid_fast(zo);
                c_state = c_state * fg + ig * tanh_fast(zj);
                float h = tanh_fast(c_state) * og;
                // pack: round h to 24-bit mantissa, tag in low 8 bits; 16 lanes
                // publish one contiguous 64B line per WG
                unsigned hb  = (__float_as_uint(h) + 0x80u) & 0xFFFFFF00u;
                unsigned pkt = hb | (unsigned)((s + 1) & 255);
                __hip_atomic_store(hslot + (((s + 1) & 1) << 10) + g * 16 + t, pkt,
                                   __ATOMIC_RELAXED, __HIP_MEMORY_SCOPE_AGENT);
                out[(size_t)s * HD + g * 16 + t] = h;  // off critical path
            }
        }
    }
}

// ---------------- launch ----------------
extern "C" void kernel_launch(void* const* d_in, const int* in_sizes, int n_in,
                              void* d_out, int out_size, void* d_ws, size_t ws_size,
                              hipStream_t stream) {
    const float* x = (const float*)d_in[0];   // [8192,1024]
    const float* W = (const float*)d_in[1];   // [2048,4096]
    const float* b = (const float*)d_in[2];   // [4096]
    float* out = (float*)d_out;               // [8192,1024]

    char* ws = (char*)d_ws;
    // ws layout: zx 128MB | hslot 16KB region (8KB used) | Wt/Whp 8MB (time-shared)
    float*          zxp   = (float*)ws;
    const size_t    ZXB   = (size_t)T_STEPS * ZD * sizeof(float);   // 134217728
    unsigned*       hslot = (unsigned*)(ws + ZXB);
    unsigned short* Wt    = (unsigned short*)(ws + ZXB + 16384);
    unsigned*       Whp   = (unsigned*)(ws + ZXB + 16384);          // reuses Wt region

    // h_0 = 0 with tag 0 in both parity slots (ws is poisoned each call)
    hipMemsetAsync(hslot, 0, 8192, stream);

    // phase 0: pack Wx -> bf16 tiles
    wt_pack<<<dim3((IN_DIM * ZD) / 256), dim3(256), 0, stream>>>(W, Wt);

    // phase 1: ZX = x @ Wx + b
    zx_gemm<<<dim3(ZD / BN, T_STEPS / BM), dim3(256), 0, stream>>>(x, Wt, b, zxp);

    // phase 0b: pack Wh -> fp16 pairs into the now-dead Wt region (stream-ordered)
    whp_pack<<<dim3(128), dim3(256), 0, stream>>>(W, Whp);

    // phase 2: sequential recurrence (cooperative for guaranteed co-residency)
    void* args[] = { (void*)&Whp, (void*)&zxp, (void*)&out, (void*)&hslot };
    hipLaunchCooperativeKernel((void*)lstm_seq, dim3(G2), dim3(B2), args, 0, stream);
}